// Round 2
// baseline (211.763 us; speedup 1.0000x reference)
//
#include <hip/hip_runtime.h>

#define BATCH 131072
#define NS 64
#define NF 128
#define NTOT 192   // NS + NF
#define WPB 4      // waves per block
#define RPW 4      // rays per wave (16 lanes per ray)
#define RPB (WPB * RPW)

// 16-lane inclusive add-scan via DPP row_shr 1/2/4/8. row_shr is row-local
// (never crosses a 16-lane row); bound_ctrl=true => invalid sources read 0.
#define DPP_ADD_F(x, ctrl)                                                   \
    x += __int_as_float(__builtin_amdgcn_update_dpp(                         \
        0, __float_as_int(x), ctrl, 0xf, 0xf, true))
#define DPP_ADD_I(x, ctrl)                                                   \
    x += __builtin_amdgcn_update_dpp(0, x, ctrl, 0xf, 0xf, true)

__device__ __forceinline__ float row_iscan_f(float x) {
    DPP_ADD_F(x, 0x111);   // row_shr:1
    DPP_ADD_F(x, 0x112);   // row_shr:2
    DPP_ADD_F(x, 0x114);   // row_shr:4
    DPP_ADD_F(x, 0x118);   // row_shr:8
    return x;
}
__device__ __forceinline__ int row_iscan_i(int x) {
    DPP_ADD_I(x, 0x111);
    DPP_ADD_I(x, 0x112);
    DPP_ADD_I(x, 0x114);
    DPP_ADD_I(x, 0x118);
    return x;
}
// broadcast lane (row*16 + 15)'s value to its whole 16-lane row.
// ds_swizzle BitMode: lane' = ((lane & and) | or) ^ xor ; and=0x10, or=0xF.
__device__ __forceinline__ float row_bcast15_f(float x) {
    return __int_as_float(__builtin_amdgcn_ds_swizzle(__float_as_int(x), 0x1F0));
}

__global__ __launch_bounds__(256) void pdf_sampler_kernel(
    const float* __restrict__ near_p,
    const float* __restrict__ far_p,
    const float* __restrict__ density,
    const float* __restrict__ rgb,
    float* __restrict__ out)
{
    const int lane = threadIdx.x & 63;
    const int wave = threadIdx.x >> 6;
    const int g    = lane >> 4;          // ray slot within wave (4 rays/wave)
    const int j    = lane & 15;          // lane within 16-lane ray group
    const int rayBase = (blockIdx.x * WPB + wave) * RPW;
    const int ray  = rayBase + g;

    // Per-ray LDS: (cdf, mid) table + union{int hist[128] ; float comb[192]}.
    // hist occupies the first 512 B of the comb region and is dead before the
    // merge scatter begins. All traffic is wave-local: DS ops from one wave
    // execute in order; wave_barrier() only fences the compiler.
    __shared__ float2 s_cm[WPB][RPW][NS];
    __shared__ __align__(16) float s_comb[WPB][RPW][NTOT];

    // ---- loads (all coalesced) -------------------------------------------
    const float nearv = near_p[ray];
    const float farv  = far_p[ray];
    // wave covers 256 contiguous density floats: lane -> samples 4j..4j+3 of ray g
    const float4 dv = *reinterpret_cast<const float4*>(
        &density[(size_t)rayBase * NS + 4 * lane]);
    // wave covers 768 contiguous rgb floats: 3 x float4 per lane
    const float4* rgbw = reinterpret_cast<const float4*>(
        &rgb[(size_t)rayBase * NS * 3]);
    const float4 c0 = rgbw[3 * lane + 0];   // r0 g0 b0 r1
    const float4 c1 = rgbw[3 * lane + 1];   // g1 b1 r2 g2
    const float4 c2 = rgbw[3 * lane + 2];   // b2 r3 g3 b3

    // ---- per-sample geometry: samples s = 4j .. 4j+3 ---------------------
    const int s0 = 4 * j;
    float mid[4], x[4];
    {
        const float dens[4] = {dv.x, dv.y, dv.z, dv.w};
        float edge[5];
        #pragma unroll
        for (int i = 0; i < 5; ++i) {
            const float u = (float)(s0 + i) * (1.0f / 64.0f);
            edge[i] = nearv * (1.0f - u) + farv * u;
        }
        #pragma unroll
        for (int i = 0; i < 4; ++i) {
            mid[i] = 0.5f * (edge[i] + edge[i + 1]);
            x[i]   = dens[i] * (edge[i + 1] - edge[i]);
        }
    }

    // ---- telescoped transmittance: local prefix + 16-lane row scan -------
    const float p0 = x[0];
    const float p1 = p0 + x[1];
    const float p2 = p1 + x[2];
    const float p3 = p2 + x[3];
    const float rinc  = row_iscan_f(p3);
    const float rexcl = rinc - p3;           // sum over samples 0..4j-1
    float e[4];
    e[0] = __expf(-(rexcl + p0));
    e[1] = __expf(-(rexcl + p1));
    e[2] = __expf(-(rexcl + p2));
    e[3] = __expf(-(rexcl + p3));
    // eprev[0] = previous lane's e[3]; 1.0 at row start (bound_ctrl=false keeps old)
    const float eprev0 = __int_as_float(__builtin_amdgcn_update_dpp(
        0x3f800000, __float_as_int(e[3]), 0x111, 0xf, 0xf, false));
    const float w0 = eprev0 - e[0];
    const float w1 = e[0] - e[1];
    const float w2 = e[1] - e[2];
    const float w3 = e[2] - e[3];

    const float elast = row_bcast15_f(e[3]);  // e at sample 63 of this ray
    const float wsum  = 1.0f - elast;
    const float rcpw  = __builtin_amdgcn_rcpf(wsum + 1e-6f);
    float cdf[4];
    cdf[0] = (1.0f - e[0]) * rcpw;
    cdf[1] = (1.0f - e[1]) * rcpw;
    cdf[2] = (1.0f - e[2]) * rcpw;
    cdf[3] = (1.0f - e[3]) * rcpw;

    // ---- stash (cdf, mid); zero histogram --------------------------------
    #pragma unroll
    for (int i = 0; i < 4; ++i)
        s_cm[wave][g][s0 + i] = make_float2(cdf[i], mid[i]);

    int*  hist = reinterpret_cast<int*>(&s_comb[wave][g][0]);
    int4* hz   = reinterpret_cast<int4*>(hist);
    hz[2 * j + 0] = make_int4(0, 0, 0, 0);
    hz[2 * j + 1] = make_int4(0, 0, 0, 0);

    // ---- t_s = first fine index k with u_k >= cdf_s ----------------------
    const float step = 0.9f / 127.0f;
    int t[4];
    #pragma unroll
    for (int i = 0; i < 4; ++i) {
        int tt = (int)ceilf((cdf[i] - 0.05f) * (127.0f / 0.9f));
        tt = tt < 0 ? 0 : (tt > 128 ? 128 : tt);
        while (tt > 0   && __fmaf_rn(step, (float)(tt - 1), 0.05f) >= cdf[i]) --tt;
        while (tt < 128 && __fmaf_rn(step, (float)tt,       0.05f) <  cdf[i]) ++tt;
        t[i] = tt;
    }

    __builtin_amdgcn_wave_barrier();
    #pragma unroll
    for (int i = 0; i < 4; ++i)
        if (t[i] < 128) atomicAdd(&hist[t[i]], 1);
    __builtin_amdgcn_wave_barrier();

    // ---- weighted reductions (row totals land in lane j==15) -------------
    const float wr = row_iscan_f(__fmaf_rn(w0, c0.x, __fmaf_rn(w1, c0.w,
                     __fmaf_rn(w2, c1.z, w3 * c2.y))));
    const float wg = row_iscan_f(__fmaf_rn(w0, c0.y, __fmaf_rn(w1, c1.x,
                     __fmaf_rn(w2, c1.w, w3 * c2.z))));
    const float wb = row_iscan_f(__fmaf_rn(w0, c0.z, __fmaf_rn(w1, c1.y,
                     __fmaf_rn(w2, c2.x, w3 * c2.w))));
    const float wm = row_iscan_f(__fmaf_rn(w0, mid[0], __fmaf_rn(w1, mid[1],
                     __fmaf_rn(w2, mid[2], w3 * mid[3]))));
    if (j == 15) {
        float* rgb_out   = out + (size_t)BATCH * NTOT;
        float* depth_out = rgb_out + (size_t)BATCH * 3;
        float* acc_out   = depth_out + BATCH;
        rgb_out[ray * 3 + 0] = wr;
        rgb_out[ray * 3 + 1] = wg;
        rgb_out[ray * 3 + 2] = wb;
        depth_out[ray] = wm * __builtin_amdgcn_rcpf(wsum + 1e-8f);
        acc_out[ray]   = wsum;
    }

    // ---- inds_k = cumsum(hist)[k]; this lane owns k = 8j .. 8j+7 ---------
    int hv[8];
    {
        const int4 a = hz[2 * j + 0];
        const int4 b = hz[2 * j + 1];
        hv[0] = a.x; hv[1] = a.y; hv[2] = a.z; hv[3] = a.w;
        hv[4] = b.x; hv[5] = b.y; hv[6] = b.z; hv[7] = b.w;
    }
    __builtin_amdgcn_wave_barrier();   // hist fully read before comb scatter
    int lp[8];
    {
        int a8 = 0;
        #pragma unroll
        for (int i = 0; i < 8; ++i) { a8 += hv[i]; lp[i] = a8; }
        const int ri = row_iscan_i(a8);
        const int re = ri - a8;
        #pragma unroll
        for (int i = 0; i < 8; ++i) lp[i] += re;
    }

    // ---- fine samples + closed-form merge scatter ------------------------
    const float2* cmg  = s_cm[wave][g];
    float*        comb = &s_comb[wave][g][0];
    #pragma unroll
    for (int i = 0; i < 8; ++i) {
        const int k   = 8 * j + i;
        const int ind = lp[i];
        const int below = ind > 0 ? ind - 1 : 0;
        const int above = ind < NS - 1 ? ind : NS - 1;
        const float2 cb = cmg[below];
        const float2 ca = cmg[above];
        float denom = ca.x - cb.x;
        if (denom < 1e-5f) denom = 1.0f;
        const float u  = __fmaf_rn(step, (float)k, 0.05f);
        const float tt = (u - cb.x) * __builtin_amdgcn_rcpf(denom);
        comb[k + below + 1] = __fmaf_rn(tt, ca.y - cb.y, cb.y);
    }
    // coarse mids: position s + t_s (s >= 1), 0 for s == 0
    #pragma unroll
    for (int i = 0; i < 4; ++i) {
        const int s = s0 + i;
        comb[s ? s + t[i] : 0] = mid[i];
    }

    __builtin_amdgcn_wave_barrier();

    // ---- coalesced write: the wave's 4 rays are contiguous (768 floats) --
    const float4* cw = reinterpret_cast<const float4*>(&s_comb[wave][0][0]);
    float4*       gw = reinterpret_cast<float4*>(out + (size_t)rayBase * NTOT);
    gw[lane]       = cw[lane];
    gw[lane + 64]  = cw[lane + 64];
    gw[lane + 128] = cw[lane + 128];
}

extern "C" void kernel_launch(void* const* d_in, const int* in_sizes, int n_in,
                              void* d_out, int out_size, void* d_ws, size_t ws_size,
                              hipStream_t stream) {
    const float* near_p  = (const float*)d_in[0];
    const float* far_p   = (const float*)d_in[1];
    const float* density = (const float*)d_in[2];
    const float* rgb     = (const float*)d_in[3];
    float* out = (float*)d_out;

    const int grid = BATCH / RPB;  // 8192 blocks of 256 threads (16 rays/block)
    pdf_sampler_kernel<<<grid, 256, 0, stream>>>(near_p, far_p, density, rgb, out);
}

// Round 5
// 211.522 us; speedup vs baseline: 1.0011x; 1.0011x over previous
//
#include <hip/hip_runtime.h>

#define BATCH 131072
#define NS 64
#define NF 128
#define NTOT 192   // NS + NF
#define WPB 4      // waves per block
#define RPW 4      // rays per wave (16 lanes per ray)
#define RPB (WPB * RPW)
// Per-ray LDS strides padded to 4 mod 32 banks so the 4 rays of a wave sit on
// disjoint bank phases (rslot*stride mod 32 = {0,4,8,12} within a wave).
#define CDF_STRIDE 68    // floats (64 + 4 pad)
#define COMB_STRIDE 196  // floats (192 + 4 pad)

// 16-lane inclusive add-scan via DPP row_shr 1/2/4/8. row_shr is row-local
// (never crosses a 16-lane row); bound_ctrl=true => invalid sources read 0.
#define DPP_ADD_F(x, ctrl)                                                   \
    x += __int_as_float(__builtin_amdgcn_update_dpp(                         \
        0, __float_as_int(x), ctrl, 0xf, 0xf, true))
#define DPP_ADD_I(x, ctrl)                                                   \
    x += __builtin_amdgcn_update_dpp(0, x, ctrl, 0xf, 0xf, true)

__device__ __forceinline__ float row_iscan_f(float x) {
    DPP_ADD_F(x, 0x111);   // row_shr:1
    DPP_ADD_F(x, 0x112);   // row_shr:2
    DPP_ADD_F(x, 0x114);   // row_shr:4
    DPP_ADD_F(x, 0x118);   // row_shr:8
    return x;
}
__device__ __forceinline__ int row_iscan_i(int x) {
    DPP_ADD_I(x, 0x111);
    DPP_ADD_I(x, 0x112);
    DPP_ADD_I(x, 0x114);
    DPP_ADD_I(x, 0x118);
    return x;
}
// broadcast lane (row*16 + 15)'s value to its whole 16-lane row.
// ds_swizzle BitMode: lane' = ((lane & and) | or) ^ xor ; and=0x10, or=0xF.
__device__ __forceinline__ float row_bcast15_f(float x) {
    return __int_as_float(__builtin_amdgcn_ds_swizzle(__float_as_int(x), 0x1F0));
}

__global__ __launch_bounds__(256) void pdf_sampler_kernel(
    const float* __restrict__ near_p,
    const float* __restrict__ far_p,
    const float* __restrict__ density,
    const float* __restrict__ rgb,
    float* __restrict__ out)
{
    const int lane = threadIdx.x & 63;
    const int wave = threadIdx.x >> 6;
    const int g    = lane >> 4;          // ray slot within wave
    const int j    = lane & 15;          // lane within 16-lane ray group
    const int rayBase = (blockIdx.x * WPB + wave) * RPW;
    const int ray   = rayBase + g;
    const int rslot = (wave << 2) | g;   // 0..15

    // Per-ray LDS: cdf table (mid is linear in s -> reconstructed in-register)
    // + union{int hist[128] ; float comb[192]} (hist dead before comb scatter).
    // All traffic is wave-local: DS ops from one wave execute in order;
    // wave_barrier() only fences the compiler.
    __shared__ float s_cdf[RPB * CDF_STRIDE];
    __shared__ __align__(16) float s_comb[RPB * COMB_STRIDE];
    float* cdfb = s_cdf  + rslot * CDF_STRIDE;   // byte base 272*rslot, 16B-aligned
    float* comb = s_comb + rslot * COMB_STRIDE;  // byte base 784*rslot, 16B-aligned
    int*   hist = reinterpret_cast<int*>(comb);

    // ---- loads (all coalesced) -------------------------------------------
    const float nearv = near_p[ray];
    const float farv  = far_p[ray];
    const float4 dv = *reinterpret_cast<const float4*>(
        &density[(size_t)rayBase * NS + 4 * lane]);
    const float4* rgbw = reinterpret_cast<const float4*>(
        &rgb[(size_t)rayBase * NS * 3]);
    const float4 c0 = rgbw[3 * lane + 0];   // r0 g0 b0 r1
    const float4 c1 = rgbw[3 * lane + 1];   // g1 b1 r2 g2
    const float4 c2 = rgbw[3 * lane + 2];   // b2 r3 g3 b3

    // ---- geometry: edge spacing is exactly Bc; mid_s = Ac + Bc*s ---------
    const float Bc = (farv - nearv) * (1.0f / 64.0f);
    const float Ac = __fmaf_rn(0.5f, Bc, nearv);
    const int s0 = 4 * j;
    float mid[4];
    #pragma unroll
    for (int i = 0; i < 4; ++i) mid[i] = __fmaf_rn(Bc, (float)(s0 + i), Ac);

    // ---- telescoped transmittance: scan density, scale by Bc once --------
    const float q0 = dv.x;
    const float q1 = q0 + dv.y;
    const float q2 = q1 + dv.z;
    const float q3 = q2 + dv.w;
    const float rexq = row_iscan_f(q3) - q3;   // density prefix, samples < 4j
    float e[4];
    e[0] = __expf(-Bc * (rexq + q0));
    e[1] = __expf(-Bc * (rexq + q1));
    e[2] = __expf(-Bc * (rexq + q2));
    e[3] = __expf(-Bc * (rexq + q3));
    // eprev[0] = previous lane's e[3]; 1.0 at row start (bound_ctrl=false keeps old)
    const float eprev0 = __int_as_float(__builtin_amdgcn_update_dpp(
        0x3f800000, __float_as_int(e[3]), 0x111, 0xf, 0xf, false));
    const float w0 = eprev0 - e[0];
    const float w1 = e[0] - e[1];
    const float w2 = e[1] - e[2];
    const float w3 = e[2] - e[3];

    const float elast = row_bcast15_f(e[3]);  // e at sample 63 of this ray
    const float wsum  = 1.0f - elast;
    const float rcpw  = __builtin_amdgcn_rcpf(wsum + 1e-6f);
    float cdf[4];
    #pragma unroll
    for (int i = 0; i < 4; ++i) cdf[i] = (1.0f - e[i]) * rcpw;

    // ---- stash cdf (one b128); zero histogram (two b128) -----------------
    *reinterpret_cast<float4*>(&cdfb[s0]) =
        make_float4(cdf[0], cdf[1], cdf[2], cdf[3]);
    int4* hz = reinterpret_cast<int4*>(hist);
    hz[2 * j + 0] = make_int4(0, 0, 0, 0);
    hz[2 * j + 1] = make_int4(0, 0, 0, 0);

    // ---- t_s = first fine index k with u_k >= cdf_s ----------------------
    // ceil error < 1e-4 index units -> at most one fixup each way (predicated).
    const float step = 0.9f / 127.0f;
    int t[4];
    #pragma unroll
    for (int i = 0; i < 4; ++i) {
        int tt = (int)ceilf((cdf[i] - 0.05f) * (127.0f / 0.9f));
        tt = tt < 0 ? 0 : (tt > 128 ? 128 : tt);
        if (tt > 0   && __fmaf_rn(step, (float)(tt - 1), 0.05f) >= cdf[i]) --tt;
        if (tt < 128 && __fmaf_rn(step, (float)tt,       0.05f) <  cdf[i]) ++tt;
        t[i] = tt;
    }

    __builtin_amdgcn_wave_barrier();
    #pragma unroll
    for (int i = 0; i < 4; ++i)
        if (t[i] < 128) atomicAdd(&hist[t[i]], 1);
    __builtin_amdgcn_wave_barrier();

    // ---- weighted reductions (row totals land in lane j==15) -------------
    const float wr = row_iscan_f(__fmaf_rn(w0, c0.x, __fmaf_rn(w1, c0.w,
                     __fmaf_rn(w2, c1.z, w3 * c2.y))));
    const float wg = row_iscan_f(__fmaf_rn(w0, c0.y, __fmaf_rn(w1, c1.x,
                     __fmaf_rn(w2, c1.w, w3 * c2.z))));
    const float wb = row_iscan_f(__fmaf_rn(w0, c0.z, __fmaf_rn(w1, c1.y,
                     __fmaf_rn(w2, c2.x, w3 * c2.w))));
    const float wm = row_iscan_f(__fmaf_rn(w0, mid[0], __fmaf_rn(w1, mid[1],
                     __fmaf_rn(w2, mid[2], w3 * mid[3]))));
    if (j == 15) {
        float* rgb_out   = out + (size_t)BATCH * NTOT;
        float* depth_out = rgb_out + (size_t)BATCH * 3;
        float* acc_out   = depth_out + BATCH;
        rgb_out[ray * 3 + 0] = wr;
        rgb_out[ray * 3 + 1] = wg;
        rgb_out[ray * 3 + 2] = wb;
        depth_out[ray] = wm * __builtin_amdgcn_rcpf(wsum + 1e-8f);
        acc_out[ray]   = wsum;
    }

    // ---- inds_k = cumsum(hist)[k]; this lane owns k = 8j .. 8j+7 ---------
    int hv[8];
    {
        const int4 a = hz[2 * j + 0];
        const int4 b = hz[2 * j + 1];
        hv[0] = a.x; hv[1] = a.y; hv[2] = a.z; hv[3] = a.w;
        hv[4] = b.x; hv[5] = b.y; hv[6] = b.z; hv[7] = b.w;
    }
    __builtin_amdgcn_wave_barrier();   // hist fully read before comb scatter
    int lp[8];
    {
        int a8 = 0;
        #pragma unroll
        for (int i = 0; i < 8; ++i) { a8 += hv[i]; lp[i] = a8; }
        const int ri = row_iscan_i(a8);
        const int re = ri - a8;
        #pragma unroll
        for (int i = 0; i < 8; ++i) lp[i] += re;
    }

    // ---- fine samples + closed-form merge scatter ------------------------
    const float step2 = 0.9f / 127.0f;
    #pragma unroll
    for (int i = 0; i < 8; ++i) {
        const int k   = 8 * j + i;
        const int ind = lp[i];
        const int below = ind > 0 ? ind - 1 : 0;
        const int above = ind < NS - 1 ? ind : NS - 1;
        const float cb = cdfb[below];
        const float ca = cdfb[above];
        float denom = ca - cb;
        if (denom < 1e-5f) denom = 1.0f;
        const float u  = __fmaf_rn(step2, (float)k, 0.05f);
        const float tt = (u - cb) * __builtin_amdgcn_rcpf(denom);
        const float mb = __fmaf_rn(Bc, (float)below, Ac);     // mid[below]
        const float dm = Bc * (float)(above - below);         // mid[a]-mid[b]
        comb[k + below + 1] = __fmaf_rn(tt, dm, mb);
    }
    // coarse mids: position s + t_s (s >= 1), 0 for s == 0
    #pragma unroll
    for (int i = 0; i < 4; ++i) {
        const int s = s0 + i;
        comb[s ? s + t[i] : 0] = mid[i];
    }

    __builtin_amdgcn_wave_barrier();

    // ---- coalesced write through the padded layout -----------------------
    // float4 index f in [0,192) per wave; ray r = f/48 via mul-shift.
    float* outw = out + (size_t)rayBase * NTOT;
    #pragma unroll
    for (int m = 0; m < 3; ++m) {
        const int f   = lane + 64 * m;
        const int r   = (f * 683) >> 15;    // f / 48 for f < 192
        const int off = f - 48 * r;
        const float4 v = *reinterpret_cast<const float4*>(
            &s_comb[((wave << 2) | r) * COMB_STRIDE + 4 * off]);
        reinterpret_cast<float4*>(outw)[f] = v;
    }
}

extern "C" void kernel_launch(void* const* d_in, const int* in_sizes, int n_in,
                              void* d_out, int out_size, void* d_ws, size_t ws_size,
                              hipStream_t stream) {
    const float* near_p  = (const float*)d_in[0];
    const float* far_p   = (const float*)d_in[1];
    const float* density = (const float*)d_in[2];
    const float* rgb     = (const float*)d_in[3];
    float* out = (float*)d_out;

    const int grid = BATCH / RPB;  // 8192 blocks of 256 threads (16 rays/block)
    pdf_sampler_kernel<<<grid, 256, 0, stream>>>(near_p, far_p, density, rgb, out);
}